// Round 6
// baseline (63.202 us; speedup 1.0000x reference)
//
#include <hip/hip_runtime.h>
#include <hip/hip_bf16.h>

// SelfContrastiveLoss: loss over E = exp(qn @ kn^T / T), B=8192, D=256.
// R6: 4-wave blocks (128x256 tile) so TWO blocks co-reside per CU at the
//     ~250-reg/wave budget (acc=128 AGPR) — cross-block overlap fills barrier/
//     epilogue stalls. BK=32 dbuf (48KB LDS), lean barriers (2/tile),
//     one-phase-ahead reads, 4-chunk XOR swizzle, XCD-region map.
//
// ws layout: qn bf16 4MB | kn bf16 4MB | diag 32KB | rowsum 32KB | colsum 32KB

#define NB 8192
#define ND 256

constexpr float EPS = 1e-5f;
// exp(x*20) == exp2(x * 20*log2(e))
constexpr float EXP2_SCALE = 28.853900817779268f;

typedef float f32x4 __attribute__((ext_vector_type(4)));
typedef short s16x8 __attribute__((ext_vector_type(8)));

#define GLOAD_LDS16(g, l)                                                  \
  __builtin_amdgcn_global_load_lds(                                        \
      (const __attribute__((address_space(1))) unsigned int*)(g),          \
      (__attribute__((address_space(3))) unsigned int*)(l), 16, 0, 0)

#define BAR()   __builtin_amdgcn_s_barrier()
#define PRIO(x) __builtin_amdgcn_s_setprio(x)

// ---------------- kernel 1: row L2-normalize -> bf16, fp32 diag, zero accums
__global__ __launch_bounds__(256) void norm_diag_kernel(
    const float* __restrict__ q, const float* __restrict__ k,
    ushort* __restrict__ qn, ushort* __restrict__ kn, float* __restrict__ diag,
    float* __restrict__ rowcol /*rowsum||colsum, 2*NB floats*/,
    float* __restrict__ out) {
  if (blockIdx.x < 64) rowcol[blockIdx.x * 256 + threadIdx.x] = 0.f;
  if (blockIdx.x == 64 && threadIdx.x == 0) out[0] = 0.f;

  const int wave = threadIdx.x >> 6;
  const int lane = threadIdx.x & 63;
  const int row = blockIdx.x * 4 + wave;          // one wave per row
  const float4* q4 = reinterpret_cast<const float4*>(q + (size_t)row * ND);
  const float4* k4 = reinterpret_cast<const float4*>(k + (size_t)row * ND);
  float4 qv = q4[lane];
  float4 kv = k4[lane];
  float sq = qv.x * qv.x + qv.y * qv.y + qv.z * qv.z + qv.w * qv.w;
  float sk = kv.x * kv.x + kv.y * kv.y + kv.z * kv.z + kv.w * kv.w;
  float dp = qv.x * kv.x + qv.y * kv.y + qv.z * kv.z + qv.w * kv.w;
#pragma unroll
  for (int m = 1; m < 64; m <<= 1) {
    sq += __shfl_xor(sq, m);
    sk += __shfl_xor(sk, m);
    dp += __shfl_xor(dp, m);
  }
  const float iq = 1.0f / fmaxf(sqrtf(sq), 1e-12f);   // F.normalize eps
  const float ik = 1.0f / fmaxf(sqrtf(sk), 1e-12f);
  union { ushort4 u; __hip_bfloat16 h[4]; } pq, pk;
  pq.h[0] = __float2bfloat16(qv.x * iq);
  pq.h[1] = __float2bfloat16(qv.y * iq);
  pq.h[2] = __float2bfloat16(qv.z * iq);
  pq.h[3] = __float2bfloat16(qv.w * iq);
  pk.h[0] = __float2bfloat16(kv.x * ik);
  pk.h[1] = __float2bfloat16(kv.y * ik);
  pk.h[2] = __float2bfloat16(kv.z * ik);
  pk.h[3] = __float2bfloat16(kv.w * ik);
  reinterpret_cast<ushort4*>(qn)[(size_t)row * (ND / 4) + lane] = pq.u;
  reinterpret_cast<ushort4*>(kn)[(size_t)row * (ND / 4) + lane] = pk.u;
  if (lane == 0) diag[row] = __expf(dp * iq * ik * 20.0f);  // exact fp32 diag
}

// ---------------- kernel 2: fused bf16 MFMA GEMM + exp + row/col reduce ------
// 128x256 tile, 4 waves (1M x 4N), wave-tile 128x64 (8x4 frags of 16x16x32).
// BK=32, double-buffered: A 128x32 (8KB) x2 + B 256x32 (16KB) x2 = 48KB.
// Chunk swizzle (4 chunks/row): LDS[r][c] holds global chunk c^((r>>1)&3).
#define BM 128
#define BN 256

__global__ __launch_bounds__(256, 2) void gemm_exp_reduce_kernel(
    const ushort* __restrict__ qn, const ushort* __restrict__ kn,
    float* __restrict__ rowsum, float* __restrict__ colsum) {
  extern __shared__ ushort smem[];   // 24576 ushorts = 48KB
  ushort* A0 = smem;                 // 4096 shorts (8KB)
  ushort* A1 = smem + 4096;
  ushort* B0 = smem + 8192;          // 8192 shorts (16KB)
  ushort* B1 = smem + 16384;

  const int tid  = threadIdx.x;
  const int lane = tid & 63;
  const int wave = tid >> 6;          // 4 waves = 4 N-strips of 64 cols
  const int wc = wave;
  const int l15 = lane & 15;
  const int lhi = lane >> 4;

  // XCD-region map: 2048 blocks, xcd gets a 16x16-tile region (~3MB < 4MB L2)
  const int lid = blockIdx.y * 32 + blockIdx.x;
  const int xcd = lid & 7;
  const int j   = lid >> 3;                       // 0..255
  const int brow = ((xcd >> 1) * 16 + (j >> 4)) * BM;
  const int bcol = ((xcd & 1) * 16 + (j & 15)) * BN;

  f32x4 acc[8][4];
#pragma unroll
  for (int mf = 0; mf < 8; ++mf)
#pragma unroll
    for (int nf = 0; nf < 4; ++nf)
      acc[mf][nf] = (f32x4){0.f, 0.f, 0.f, 0.f};

  // stage: A 512 chunks (2/thread), B 1024 chunks (4/thread); lane-linear dest
  auto stageA = [&](int kt, ushort* Adst) {
#pragma unroll
    for (int p = 0; p < 2; ++p) {
      const int f   = p * 256 + tid;        // 0..511
      const int row = f >> 2;               // 0..127
      const int gch = (f & 3) ^ ((row >> 1) & 3);
      GLOAD_LDS16(&qn[(size_t)(brow + row) * ND + kt * 32 + gch * 8],
                  Adst + (size_t)f * 8);
    }
  };
  auto stageB = [&](int kt, ushort* Bdst) {
#pragma unroll
    for (int p = 0; p < 4; ++p) {
      const int f   = p * 256 + tid;        // 0..1023
      const int row = f >> 2;               // 0..255
      const int gch = (f & 3) ^ ((row >> 1) & 3);
      GLOAD_LDS16(&kn[(size_t)(bcol + row) * ND + kt * 32 + gch * 8],
                  Bdst + (size_t)f * 8);
    }
  };

  // swizzled fragment reads (<=2-way bank aliasing = free)
  auto ldA = [&](s16x8* dst, const ushort* base, int half) {
#pragma unroll
    for (int mf = 0; mf < 4; ++mf) {
      const int r  = (half * 4 + mf) * 16 + l15;
      const int sc = lhi ^ ((r >> 1) & 3);
      dst[mf] = *reinterpret_cast<const s16x8*>(base + r * 32 + sc * 8);
    }
  };
  auto ldB = [&](s16x8* dst, const ushort* base) {
#pragma unroll
    for (int nf = 0; nf < 4; ++nf) {
      const int r  = wc * 64 + nf * 16 + l15;
      const int sc = lhi ^ ((r >> 1) & 3);
      dst[nf] = *reinterpret_cast<const s16x8*>(base + r * 32 + sc * 8);
    }
  };
  auto mm = [&](const s16x8* a, const s16x8* b, int half) {
#pragma unroll
    for (int mf = 0; mf < 4; ++mf)
#pragma unroll
      for (int nf = 0; nf < 4; ++nf)
        acc[half * 4 + mf][nf] = __builtin_amdgcn_mfma_f32_16x16x32_bf16(
            a[mf], b[nf], acc[half * 4 + mf][nf], 0, 0, 0);
  };

  s16x8 afA[4], afB[4], bfA[4], bfB[4];

  // Per tile: lean barriers (fence-BAR + end-BAR). Reads one phase ahead.
  // Entering: afA = A m0-3 (this tile), bcur = B (this tile).
  auto tile = [&](const ushort* Ab, const ushort* Bb, ushort* An, ushort* Bn,
                  int ktn, s16x8* bcur, s16x8* bnxt, bool do_stage,
                  bool read_next) {
    if (do_stage) { stageA(ktn, An); stageB(ktn, Bn); }  // 6 vmem for t+1
    ldA(afB, Ab, 1);                                      // this tile m4-7
    PRIO(1); mm(afA, bcur, 0); PRIO(0);
    if (read_next) {
      asm volatile("s_waitcnt vmcnt(0)" ::: "memory");    // t+1 landed (issued
      BAR();                                              //  a full phase ago)
      ldA(afA, An, 0);                                    // next tile m0-3
      ldB(bnxt, Bn);                                      // next tile B
    }
    PRIO(1); mm(afB, bcur, 1); PRIO(0);
    BAR();                                                // tile's reads done
  };

  // prologue
  stageA(0, A0);
  stageB(0, B0);
  asm volatile("s_waitcnt vmcnt(0)" ::: "memory");
  BAR();
  ldA(afA, A0, 0);
  ldB(bfA, B0);

  tile(A0, B0, A1, B1, 1, bfA, bfB, true, true);
  tile(A1, B1, A0, B0, 2, bfB, bfA, true, true);
  tile(A0, B0, A1, B1, 3, bfA, bfB, true, true);
  tile(A1, B1, A0, B0, 4, bfB, bfA, true, true);
  tile(A0, B0, A1, B1, 5, bfA, bfB, true, true);
  tile(A1, B1, A0, B0, 6, bfB, bfA, true, true);
  tile(A0, B0, A1, B1, 7, bfA, bfB, true, true);
  tile(A1, B1, A0, B0, 0, bfB, bfA, false, false);

  // ---- epilogue: E = exp2(S*scale), LDS transpose-reduce, 1 atomic/entry ----
#pragma unroll
  for (int mf = 0; mf < 8; ++mf)
#pragma unroll
    for (int nf = 0; nf < 4; ++nf)
#pragma unroll
      for (int j2 = 0; j2 < 4; ++j2)
        acc[mf][nf][j2] = exp2f(acc[mf][nf][j2] * EXP2_SCALE);

  __syncthreads();                       // compute done; reuse smem
  float* RS = reinterpret_cast<float*>(smem);          // [128][66] row partials
  float* CS = RS + 128 * 66;                           // [256][5]  col partials

  // row partials: per (row, 16-col group): col idx = wc*16+l15
#pragma unroll
  for (int mf = 0; mf < 8; ++mf) {
    f32x4 s = acc[mf][0] + acc[mf][1] + acc[mf][2] + acc[mf][3];
    const int rowb = mf * 16 + lhi * 4;
    const int col  = wc * 16 + l15;
#pragma unroll
    for (int j2 = 0; j2 < 4; ++j2) RS[(rowb + j2) * 66 + col] = s[j2];
  }
  // col partials: per col (wave-unique), 4 lhi partials
#pragma unroll
  for (int nf = 0; nf < 4; ++nf) {
    float cs = 0.f;
#pragma unroll
    for (int mf = 0; mf < 8; ++mf)
#pragma unroll
      for (int j2 = 0; j2 < 4; ++j2) cs += acc[mf][nf][j2];
    CS[(wc * 64 + nf * 16 + l15) * 5 + lhi] = cs;
  }
  __syncthreads();
  {
    const int r = tid >> 1, h = tid & 1;   // 2 threads per row
    f32x4 p = (f32x4){0.f, 0.f, 0.f, 0.f};
#pragma unroll
    for (int c = 0; c < 8; ++c)
      p += *reinterpret_cast<const f32x4*>(&RS[r * 66 + h * 32 + c * 4]);
    float s = p[0] + p[1] + p[2] + p[3];
    s += __shfl_xor(s, 1);
    if (h == 0) atomicAdd(&rowsum[brow + r], s);
  }
  {
    const int c = tid;                     // 1 thread per col
    const float sc = CS[c * 5 + 0] + CS[c * 5 + 1] + CS[c * 5 + 2] + CS[c * 5 + 3];
    atomicAdd(&colsum[bcol + c], sc);
  }
}

// ---------------- kernel 3: final scalar loss (parallel, 32 blocks) ----------
__global__ __launch_bounds__(256) void loss_kernel(
    const float* __restrict__ diag, const float* __restrict__ rowsum,
    const float* __restrict__ colsum, float* __restrict__ out) {
  float acc = 0.f;
  for (int i = blockIdx.x * 256 + threadIdx.x; i < NB; i += 32 * 256) {
    const float d = diag[i];
    acc -= __logf(d / rowsum[i] + EPS);
    acc -= __logf(d / colsum[i] + EPS);
  }
#pragma unroll
  for (int m = 1; m < 64; m <<= 1) acc += __shfl_xor(acc, m);
  __shared__ float ls[4];
  const int wave = threadIdx.x >> 6;
  if ((threadIdx.x & 63) == 0) ls[wave] = acc;
  __syncthreads();
  if (threadIdx.x == 0)
    atomicAdd(out, (ls[0] + ls[1] + ls[2] + ls[3]) * (1.0f / NB));
}

extern "C" void kernel_launch(void* const* d_in, const int* in_sizes, int n_in,
                              void* d_out, int out_size, void* d_ws, size_t ws_size,
                              hipStream_t stream) {
  const float* q = (const float*)d_in[0];
  const float* k = (const float*)d_in[1];
  char* ws = (char*)d_ws;
  ushort* qn   = (ushort*)ws;                                   // 4 MB
  ushort* kn   = (ushort*)(ws + (size_t)NB * ND * 2);           // 4 MB
  float*  diag = (float*)(ws + (size_t)NB * ND * 4);            // 32 KB
  float*  rowsum = diag + NB;                                   // 32 KB
  float*  colsum = rowsum + NB;                                 // 32 KB
  float*  out = (float*)d_out;

  (void)hipFuncSetAttribute((const void*)gemm_exp_reduce_kernel,
                            hipFuncAttributeMaxDynamicSharedMemorySize, 49152);

  norm_diag_kernel<<<NB / 4, 256, 0, stream>>>(q, k, qn, kn, diag, rowsum, out);
  gemm_exp_reduce_kernel<<<dim3(NB / BN, NB / BM), 256, 49152, stream>>>(
      qn, kn, rowsum, colsum);
  loss_kernel<<<32, 256, 0, stream>>>(diag, rowsum, colsum, out);
}